// Round 8
// baseline (335.706 us; speedup 1.0000x reference)
//
#include <hip/hip_runtime.h>

#define DT 0.001f
#define TAU_SYN_INV 200.0f
#define V_TH 1.0f

// Native vector type — __builtin_nontemporal_* requires a true vector, not
// HIP's struct-based float4.
typedef float vfloat4 __attribute__((ext_vector_type(4)));
typedef unsigned long long u64;

// B,C,H,W = 16,64,128,128 ; N = 16777216 ; HW = 16384 elems = 4096 float4
// EPT=8, block-contiguous (R7-measured best structure). This round's single
// variable: loads switch NT -> agent-scope (sc1). Agent-scope loads bypass
// the per-XCD L2 (coherence point is the MALL) but still hit/allocate in the
// 256 MB MALL — combining NT's L2-bypass win (R4: -19us) with the ~100 MB of
// MALL input hits R4's FETCH_SIZE=98MB proved exist for cached loads.
#define EPT 8

// Agent-scope (device) relaxed load: compiles to global_load_dwordx2 ... sc1.
// No 128-bit atomic load exists, so a float4 is two 8-byte loads.
__device__ __forceinline__ vfloat4 load_agent(const vfloat4* p) {
    union { u64 u[2]; vfloat4 f; } t;
    const u64* q = (const u64*)p;
    t.u[0] = __hip_atomic_load(&q[0], __ATOMIC_RELAXED, __HIP_MEMORY_SCOPE_AGENT);
    t.u[1] = __hip_atomic_load(&q[1], __ATOMIC_RELAXED, __HIP_MEMORY_SCOPE_AGENT);
    return t.f;
}

__device__ __forceinline__ void lif_step(const vfloat4 v, const vfloat4 c,
                                         const vfloat4 xx, const float dt_tau,
                                         vfloat4& z, vfloat4& vn, vfloat4& in_)
{
    const float isyn_decay = 1.0f - DT * TAU_SYN_INV;   // 0.8
    #pragma unroll
    for (int k = 0; k < 4; ++k) {
        float vd = fmaf(dt_tau, c[k] - v[k], v[k]);
        bool s = vd > V_TH;
        z[k]   = s ? 1.0f : 0.0f;
        vn[k]  = s ? 0.0f : vd;
        in_[k] = fmaf(isyn_decay, c[k], xx[k]);
    }
}

__global__ __launch_bounds__(256) void trf_kernel(
    const vfloat4* __restrict__ x,
    const vfloat4* __restrict__ v0,
    const vfloat4* __restrict__ icur,
    const float*   __restrict__ ps,
    vfloat4* __restrict__ out_z,
    vfloat4* __restrict__ out_v,
    vfloat4* __restrict__ out_i,
    int n4)
{
    // Block-contiguous indexing: i_k = blockBase + k*256 + tid
    const int base = blockIdx.x * (blockDim.x * EPT) + threadIdx.x;

    if (base + (EPT - 1) * 256 < n4) {
        vfloat4 vv[EPT], cc[EPT], xxv[EPT];

        // 48 agent-scope loads batched, stream-major.
        #pragma unroll
        for (int k = 0; k < EPT; ++k)
            vv[k] = load_agent(&v0[base + k * 256]);
        #pragma unroll
        for (int k = 0; k < EPT; ++k)
            cc[k] = load_agent(&icur[base + k * 256]);
        #pragma unroll
        for (int k = 0; k < EPT; ++k)
            xxv[k] = load_agent(&x[base + k * 256]);

        // channel = (i4 / 4096) % 64 — wave-uniform
        float dt[EPT];
        #pragma unroll
        for (int k = 0; k < EPT; ++k)
            dt[k] = DT * ps[((base + k * 256) >> 12) & 63];

        vfloat4 z[EPT], vn[EPT], in_[EPT];
        #pragma unroll
        for (int k = 0; k < EPT; ++k)
            lif_step(vv[k], cc[k], xxv[k], dt[k], z[k], vn[k], in_[k]);

        // Stream-major NT store bursts (NT-vs-plain measured neutral, R5).
        #pragma unroll
        for (int k = 0; k < EPT; ++k)
            __builtin_nontemporal_store(z[k],   &out_z[base + k * 256]);
        #pragma unroll
        for (int k = 0; k < EPT; ++k)
            __builtin_nontemporal_store(vn[k],  &out_v[base + k * 256]);
        #pragma unroll
        for (int k = 0; k < EPT; ++k)
            __builtin_nontemporal_store(in_[k], &out_i[base + k * 256]);
    } else {
        // Tail (never taken at this shape: 2048*2048 == n4 exactly)
        #pragma unroll
        for (int k = 0; k < EPT; ++k) {
            int i = base + k * 256;
            if (i < n4) {
                const vfloat4 v  = load_agent(&v0[i]);
                const vfloat4 c  = load_agent(&icur[i]);
                const vfloat4 xx = load_agent(&x[i]);
                const float dt_tau = DT * ps[(i >> 12) & 63];
                vfloat4 zz, vnn, inn;
                lif_step(v, c, xx, dt_tau, zz, vnn, inn);
                __builtin_nontemporal_store(zz,  &out_z[i]);
                __builtin_nontemporal_store(vnn, &out_v[i]);
                __builtin_nontemporal_store(inn, &out_i[i]);
            }
        }
    }
}

extern "C" void kernel_launch(void* const* d_in, const int* in_sizes, int n_in,
                              void* d_out, int out_size, void* d_ws, size_t ws_size,
                              hipStream_t stream) {
    const float* x  = (const float*)d_in[0];
    const float* v0 = (const float*)d_in[1];
    const float* i0 = (const float*)d_in[2];
    const float* ps = (const float*)d_in[3];

    const int N  = in_sizes[0];          // 16777216
    const int n4 = N / 4;                // 4194304

    float* out = (float*)d_out;
    vfloat4* out_z = (vfloat4*)out;
    vfloat4* out_v = (vfloat4*)(out + (size_t)N);
    vfloat4* out_i = (vfloat4*)(out + 2 * (size_t)N);

    const int block = 256;
    const int grid  = (n4 + block * EPT - 1) / (block * EPT);  // 2048 blocks

    trf_kernel<<<grid, block, 0, stream>>>(
        (const vfloat4*)x, (const vfloat4*)v0, (const vfloat4*)i0, ps,
        out_z, out_v, out_i, n4);
}

// Round 9
// 321.675 us; speedup vs baseline: 1.0436x; 1.0436x over previous
//
#include <hip/hip_runtime.h>

#define DT 0.001f
#define TAU_SYN_INV 200.0f
#define V_TH 1.0f

// Native vector type — __builtin_nontemporal_* requires a true vector, not
// HIP's struct-based float4.
typedef float vfloat4 __attribute__((ext_vector_type(4)));

// B,C,H,W = 16,64,128,128 ; N = 16777216 ; HW = 16384 elems = 4096 float4
// EPT=8, WAVE-contiguous: each wave owns 8 consecutive 64-float4 lines
// (8 KB sequential run) per stream, vs R7's 1 KB chunks at 4 KB stride.
// Loads NT (measured best: R4 +18.6us cached, R8 +13.9us sc1), stores NT
// (R5: neutral vs plain). 2048 blocks.
#define EPT 8

__device__ __forceinline__ void lif_step(const vfloat4 v, const vfloat4 c,
                                         const vfloat4 xx, const float dt_tau,
                                         vfloat4& z, vfloat4& vn, vfloat4& in_)
{
    const float isyn_decay = 1.0f - DT * TAU_SYN_INV;   // 0.8
    #pragma unroll
    for (int k = 0; k < 4; ++k) {
        float vd = fmaf(dt_tau, c[k] - v[k], v[k]);
        bool s = vd > V_TH;
        z[k]   = s ? 1.0f : 0.0f;
        vn[k]  = s ? 0.0f : vd;
        in_[k] = fmaf(isyn_decay, c[k], xx[k]);
    }
}

__global__ __launch_bounds__(256) void trf_kernel(
    const vfloat4* __restrict__ x,
    const vfloat4* __restrict__ v0,
    const vfloat4* __restrict__ icur,
    const float*   __restrict__ ps,
    vfloat4* __restrict__ out_z,
    vfloat4* __restrict__ out_v,
    vfloat4* __restrict__ out_i,
    int n4)
{
    // Wave-contiguous indexing: wave wid owns [blockBase + wid*EPT*64,
    // blockBase + (wid+1)*EPT*64); access k reads 64 consecutive float4.
    const int wid  = threadIdx.x >> 6;
    const int lane = threadIdx.x & 63;
    const int base = blockIdx.x * (blockDim.x * EPT) + wid * (EPT * 64) + lane;

    if (base + (EPT - 1) * 64 < n4) {
        vfloat4 vv[EPT], cc[EPT], xxv[EPT];

        // 24 NT loads batched, stream-major; each wave's k-sequence is a
        // sequential 8 KB run per stream.
        #pragma unroll
        for (int k = 0; k < EPT; ++k)
            vv[k] = __builtin_nontemporal_load(&v0[base + k * 64]);
        #pragma unroll
        for (int k = 0; k < EPT; ++k)
            cc[k] = __builtin_nontemporal_load(&icur[base + k * 64]);
        #pragma unroll
        for (int k = 0; k < EPT; ++k)
            xxv[k] = __builtin_nontemporal_load(&x[base + k * 64]);

        // channel = (i4 / 4096) % 64 — wave-uniform (64-aligned 64-runs
        // never cross a 4096-float4 channel boundary)
        float dt[EPT];
        #pragma unroll
        for (int k = 0; k < EPT; ++k)
            dt[k] = DT * ps[((base + k * 64) >> 12) & 63];

        vfloat4 z[EPT], vn[EPT], in_[EPT];
        #pragma unroll
        for (int k = 0; k < EPT; ++k)
            lif_step(vv[k], cc[k], xxv[k], dt[k], z[k], vn[k], in_[k]);

        // Stream-major NT store bursts, wave-sequential runs.
        #pragma unroll
        for (int k = 0; k < EPT; ++k)
            __builtin_nontemporal_store(z[k],   &out_z[base + k * 64]);
        #pragma unroll
        for (int k = 0; k < EPT; ++k)
            __builtin_nontemporal_store(vn[k],  &out_v[base + k * 64]);
        #pragma unroll
        for (int k = 0; k < EPT; ++k)
            __builtin_nontemporal_store(in_[k], &out_i[base + k * 64]);
    } else {
        // Tail (never taken at this shape: 2048 blocks * 2048 == n4 exactly)
        #pragma unroll
        for (int k = 0; k < EPT; ++k) {
            int i = base + k * 64;
            if (i < n4) {
                const vfloat4 v  = __builtin_nontemporal_load(&v0[i]);
                const vfloat4 c  = __builtin_nontemporal_load(&icur[i]);
                const vfloat4 xx = __builtin_nontemporal_load(&x[i]);
                const float dt_tau = DT * ps[(i >> 12) & 63];
                vfloat4 zz, vnn, inn;
                lif_step(v, c, xx, dt_tau, zz, vnn, inn);
                __builtin_nontemporal_store(zz,  &out_z[i]);
                __builtin_nontemporal_store(vnn, &out_v[i]);
                __builtin_nontemporal_store(inn, &out_i[i]);
            }
        }
    }
}

extern "C" void kernel_launch(void* const* d_in, const int* in_sizes, int n_in,
                              void* d_out, int out_size, void* d_ws, size_t ws_size,
                              hipStream_t stream) {
    const float* x  = (const float*)d_in[0];
    const float* v0 = (const float*)d_in[1];
    const float* i0 = (const float*)d_in[2];
    const float* ps = (const float*)d_in[3];

    const int N  = in_sizes[0];          // 16777216
    const int n4 = N / 4;                // 4194304

    float* out = (float*)d_out;
    vfloat4* out_z = (vfloat4*)out;
    vfloat4* out_v = (vfloat4*)(out + (size_t)N);
    vfloat4* out_i = (vfloat4*)(out + 2 * (size_t)N);

    const int block = 256;
    const int grid  = (n4 + block * EPT - 1) / (block * EPT);  // 2048 blocks

    trf_kernel<<<grid, block, 0, stream>>>(
        (const vfloat4*)x, (const vfloat4*)v0, (const vfloat4*)i0, ps,
        out_z, out_v, out_i, n4);
}